// Round 19
// baseline (315.590 us; speedup 1.0000x reference)
//
#include <hip/hip_runtime.h>
#include <hip/hip_bf16.h>

#define NEG_SLOPE 0.2f

typedef __attribute__((ext_vector_type(8))) short bf16x8;
typedef __attribute__((ext_vector_type(4))) float f32x4;

__device__ __forceinline__ unsigned short bf16bits(float f) {
    __hip_bfloat16 t = __float2bfloat16(f);
    return *reinterpret_cast<unsigned short*>(&t);
}

// MFMA node transform: 256 threads = 4 waves; block computes 64 nodes x FOUT.
template <int FIN, int FOUT>
__global__ __launch_bounds__(256) void node_linear(
    const float* __restrict__ x, const float* __restrict__ W,
    const float* __restrict__ att_s, const float* __restrict__ att_d,
    __hip_bfloat16* __restrict__ h, float* __restrict__ a_s, float* __restrict__ a_d, int n)
{
    constexpr int RS = FIN + 8;               // padded stride (bf16 units)
    __shared__ unsigned short xt[64 * RS];
    __shared__ unsigned short Wt[FOUT * RS];
    const int tid = threadIdx.x;
    const int base = blockIdx.x * 64;

    for (int i = tid; i < 64 * FIN / 2; i += 256) {
        int node = i / (FIN / 2);
        int k2 = i % (FIN / 2);
        float2 v = make_float2(0.f, 0.f);
        if (base + node < n) v = *(const float2*)(x + (size_t)(base + node) * FIN + k2 * 2);
        unsigned pk = (unsigned)bf16bits(v.x) | ((unsigned)bf16bits(v.y) << 16);
        *(unsigned*)(&xt[node * RS + k2 * 2]) = pk;
    }
    for (int i = tid; i < FIN * FOUT; i += 256) {
        int k = i / FOUT, f = i % FOUT;
        Wt[f * RS + k] = bf16bits(W[i]);
    }
    __syncthreads();

    const int wv = tid >> 6, lane = tid & 63;
    const int m = lane & 15, b = lane >> 4;
    const int node0 = base + wv * 16;

    float ps[4] = {0,0,0,0}, pd[4] = {0,0,0,0};
    #pragma unroll
    for (int t = 0; t < FOUT / 16; ++t) {
        f32x4 acc = {0.f, 0.f, 0.f, 0.f};
        #pragma unroll
        for (int ks = 0; ks < FIN / 32; ++ks) {
            bf16x8 a  = *(const bf16x8*)(&xt[(wv * 16 + m) * RS + ks * 32 + b * 8]);
            bf16x8 bb = *(const bf16x8*)(&Wt[(t * 16 + m) * RS + ks * 32 + b * 8]);
            acc = __builtin_amdgcn_mfma_f32_16x16x32_bf16(a, bb, acc, 0, 0, 0);
        }
        const float as_c = att_s[t * 16 + m];
        const float ad_c = att_d[t * 16 + m];
        #pragma unroll
        for (int r = 0; r < 4; ++r) {
            float v = acc[r];
            int node = node0 + b * 4 + r;
            if (node < n) h[(size_t)node * FOUT + t * 16 + m] = __float2bfloat16(v);
            ps[r] = fmaf(v, as_c, ps[r]);
            pd[r] = fmaf(v, ad_c, pd[r]);
        }
    }
    #pragma unroll
    for (int r = 0; r < 4; ++r) {
        float s = ps[r], d = pd[r];
        #pragma unroll
        for (int o = 8; o > 0; o >>= 1) { s += __shfl_xor(s, o); d += __shfl_xor(d, o); }
        int node = node0 + b * 4 + r;
        if (m == 0 && node < n) { a_s[node] = s; a_d[node] = d; }
    }
}

// ---- CSR build: SB hist -> tiny scan -> per-chunk SB bin -> per-SB sort ----

__global__ __launch_bounds__(256) void sb_hist(
    const int* __restrict__ edst, int E, int n, int* __restrict__ sbhist)
{
    __shared__ int lh[256];
    const int tid = threadIdx.x;
    lh[tid] = 0;
    __syncthreads();
    const int Etot = E + n;
    const int stride = gridDim.x * 256;
    for (int i = blockIdx.x * 256 + tid; i < Etot; i += stride) {
        int d = (i < E) ? edst[i] : i - E;
        atomicAdd(&lh[d >> 9], 1);
    }
    __syncthreads();
    if (lh[tid] > 0) atomicAdd(&sbhist[tid], lh[tid]);
}

__global__ __launch_bounds__(256) void sb_scan(
    const int* __restrict__ sbhist, int nsb, int Etot,
    int* __restrict__ sbbase, int* __restrict__ sbcur)
{
    __shared__ int buf[256];
    const int tid = threadIdx.x;
    int v = (tid < nsb) ? sbhist[tid] : 0;
    buf[tid] = v;
    __syncthreads();
    for (int off = 1; off < 256; off <<= 1) {
        int t = (tid >= off) ? buf[tid - off] : 0;
        __syncthreads();
        buf[tid] += t;
        __syncthreads();
    }
    if (tid < nsb) {
        int ex = buf[tid] - v;
        sbbase[tid] = ex;
        sbcur[tid] = ex;
    }
    if (tid == 0) sbbase[nsb] = Etot;
}

#define CB_CHUNK 4096
#define CB_NSB_MAX 256
__global__ __launch_bounds__(256) void chunk_bin(
    const int* __restrict__ esrc, const int* __restrict__ edst, int E, int n,
    int nsb, int* __restrict__ sbcur, int* __restrict__ packed1)
{
    __shared__ int pk[CB_CHUNK];
    __shared__ unsigned short sbv[CB_CHUNK];
    __shared__ int hist[CB_NSB_MAX];
    __shared__ int gbase[CB_NSB_MAX];
    const int tid = threadIdx.x;
    const int i0 = blockIdx.x * CB_CHUNK;
    const int Etot = E + n;

    hist[tid] = 0;
    __syncthreads();

    for (int j = tid; j < CB_CHUNK; j += 256) {
        int i = i0 + j;
        if (i < Etot) {
            int s, d;
            if (i < E) { s = esrc[i]; d = edst[i]; }
            else       { s = d = i - E; }
            int sb = d >> 9;
            pk[j] = ((d & 511) << 17) | s;
            sbv[j] = (unsigned short)sb;
            atomicAdd(&hist[sb], 1);
        } else {
            sbv[j] = 0xFFFFu;
        }
    }
    __syncthreads();

    if (tid < nsb && hist[tid] > 0)
        gbase[tid] = atomicAdd(&sbcur[tid], hist[tid]);
    hist[tid] = 0;
    __syncthreads();

    for (int j = tid; j < CB_CHUNK; j += 256) {
        unsigned short sb = sbv[j];
        if (sb != 0xFFFFu) {
            int pos = gbase[sb] + atomicAdd(&hist[sb], 1);
            packed1[pos] = pk[j];
        }
    }
}

__global__ __launch_bounds__(256) void sb_sort2(
    const int* __restrict__ sbbase, const int* __restrict__ packed1,
    int* __restrict__ col, int* __restrict__ row_end, int n)
{
    const int sb = blockIdx.x;
    const int node0 = sb << 9;
    const int lo = sbbase[sb];
    const int hi = sbbase[sb + 1];
    const int tid = threadIdx.x;
    __shared__ int c[512];
    __shared__ int sc[512];
    c[tid] = 0; c[tid + 256] = 0;
    __syncthreads();
    for (int j = lo + tid; j < hi; j += 256)
        atomicAdd(&c[((unsigned)packed1[j]) >> 17], 1);
    __syncthreads();
    sc[tid] = c[tid]; sc[tid + 256] = c[tid + 256];
    __syncthreads();
    for (int off = 1; off < 512; off <<= 1) {
        int i0 = tid, i1 = tid + 256;
        int v0 = (i0 >= off) ? sc[i0 - off] : 0;
        int v1 = (i1 >= off) ? sc[i1 - off] : 0;
        __syncthreads();
        sc[i0] += v0; sc[i1] += v1;
        __syncthreads();
    }
    #pragma unroll
    for (int q = 0; q < 2; ++q) {
        int i = tid + q * 256;
        int node = node0 + i;
        if (node < n) row_end[node] = lo + sc[i];
        c[i] = lo + sc[i] - c[i];
    }
    __syncthreads();
    for (int j = lo + tid; j < hi; j += 256) {
        int p = packed1[j];
        int ld = ((unsigned)p) >> 17;
        int pos = atomicAdd(&c[ld], 1);
        col[pos] = p & 0x1FFFF;
    }
}

// ---- Aggregation (v2) + optional fused next-layer transform (NFOUT>0).
// Aggregate: LPN=FOUT/4 lanes/node, 4 bf16 feats/lane via uint2; lane-split
// scores; group-uniform kmax. Fusion: block's nodes' full output rows staged
// to LDS; 256 threads do the 16xFOUTxNFOUT GEMM + att reduce on idle VALU
// slots; writes next-layer bf16 h and a_s/a_d (ping-pong buffers).
template <int FOUT, int NFOUT>
__global__ __launch_bounds__(256) void gat_aggregate(
    const int* __restrict__ row_end, const int* __restrict__ col,
    const float* __restrict__ a_s, const float* __restrict__ a_d,
    const __hip_bfloat16* __restrict__ h_, const float* __restrict__ bias,
    float* __restrict__ outp, int n, int do_relu,
    const float* __restrict__ Wn, const float* __restrict__ att_s_n,
    const float* __restrict__ att_d_n, __hip_bfloat16* __restrict__ h_out,
    float* __restrict__ a_s_out, float* __restrict__ a_d_out)
{
    constexpr int LPN = FOUT / 4;
    constexpr int NPB = 256 / LPN;             // nodes per block
    const unsigned short* h = (const unsigned short*)h_;
    const int lane = threadIdx.x & 63;
    const int nl = (threadIdx.x >> 6) * (64 / LPN) + lane / LPN;  // local node
    const int node = blockIdx.x * NPB + nl;
    const int lsub = lane % LPN;
    const bool active = (node < n);
    const int end = active ? row_end[node] : 0;
    const int start = (active && node > 0) ? row_end[node - 1] : 0;
    const float adn = active ? a_d[node] : 0.f;
    const int egrp = lane & ~(LPN - 1);
    float acc0 = 0.f, acc1 = 0.f, acc2 = 0.f, acc3 = 0.f, den = 1.f;
    if (active) den = 0.f;
    for (int j = start; j < end; j += LPN) {
        int kmax = end - j; if (kmax > LPN) kmax = LPN;
        int k_idx = j + lsub;
        int sown = col[(k_idx < end) ? k_idx : (end - 1)];
        float eown = a_s[sown] + adn;
        eown = (eown > 0.f) ? eown : NEG_SLOPE * eown;
        float pown = (lsub < kmax) ? __expf(eown) : 0.f;
        for (int k = 0; k < kmax; ++k) {
            int   sk = __shfl(sown, egrp + k);
            float pk = __shfl(pown, egrp + k);
            den += pk;
            uint2 hv = *(const uint2*)(h + (size_t)sk * FOUT + lsub * 4);
            acc0 = fmaf(pk, __uint_as_float(hv.x << 16), acc0);
            acc1 = fmaf(pk, __uint_as_float(hv.x & 0xFFFF0000u), acc1);
            acc2 = fmaf(pk, __uint_as_float(hv.y << 16), acc2);
            acc3 = fmaf(pk, __uint_as_float(hv.y & 0xFFFF0000u), acc3);
        }
    }
    const float4 b4 = *(const float4*)(bias + lsub * 4);
    float inv = 1.f / den;
    float v0 = acc0 * inv + b4.x;
    float v1 = acc1 * inv + b4.y;
    float v2 = acc2 * inv + b4.z;
    float v3 = acc3 * inv + b4.w;
    if (do_relu) {
        v0 = fmaxf(v0, 0.f); v1 = fmaxf(v1, 0.f);
        v2 = fmaxf(v2, 0.f); v3 = fmaxf(v3, 0.f);
    }
    if (active) {
        float4 o; o.x = v0; o.y = v1; o.z = v2; o.w = v3;
        *(float4*)(outp + (size_t)node * FOUT + lsub * 4) = o;
    }
    if constexpr (NFOUT > 0) {
        __shared__ float vs[NPB][FOUT + 4];
        vs[nl][lsub * 4 + 0] = v0;
        vs[nl][lsub * 4 + 1] = v1;
        vs[nl][lsub * 4 + 2] = v2;
        vs[nl][lsub * 4 + 3] = v3;
        __syncthreads();
        constexpr int FB = NFOUT / 4;
        const int t = threadIdx.x;
        if (t < NPB * FB) {
            const int nl2 = t / FB, fb = t % FB;
            const int node2 = blockIdx.x * NPB + nl2;
            float g0 = 0.f, g1 = 0.f, g2 = 0.f, g3 = 0.f;
            const float* wp = Wn + fb * 4;
            #pragma unroll 4
            for (int k = 0; k < FOUT; ++k) {
                float xv = vs[nl2][k];
                float4 w = *(const float4*)(wp + (size_t)k * NFOUT);
                g0 = fmaf(xv, w.x, g0); g1 = fmaf(xv, w.y, g1);
                g2 = fmaf(xv, w.z, g2); g3 = fmaf(xv, w.w, g3);
            }
            const float4 as4 = *(const float4*)(att_s_n + fb * 4);
            const float4 ad4 = *(const float4*)(att_d_n + fb * 4);
            float ps = g0 * as4.x + g1 * as4.y + g2 * as4.z + g3 * as4.w;
            float pd = g0 * ad4.x + g1 * ad4.y + g2 * ad4.z + g3 * ad4.w;
            #pragma unroll
            for (int o = FB / 2; o > 0; o >>= 1) {
                ps += __shfl_xor(ps, o);
                pd += __shfl_xor(pd, o);
            }
            if (node2 < n) {
                unsigned w0 = (unsigned)bf16bits(g0) | ((unsigned)bf16bits(g1) << 16);
                unsigned w1 = (unsigned)bf16bits(g2) | ((unsigned)bf16bits(g3) << 16);
                uint2 pk; pk.x = w0; pk.y = w1;
                *(uint2*)((unsigned short*)h_out + (size_t)node2 * NFOUT + fb * 4) = pk;
                if (fb == 0) { a_s_out[node2] = ps; a_d_out[node2] = pd; }
            }
        }
    }
}

extern "C" void kernel_launch(void* const* d_in, const int* in_sizes, int n_in,
                              void* d_out, int out_size, void* d_ws, size_t ws_size,
                              hipStream_t stream)
{
    const float* x   = (const float*)d_in[0];
    const int* eidx  = (const int*)d_in[1];
    const float* W1  = (const float*)d_in[2];
    const float* as1 = (const float*)d_in[3];
    const float* ad1 = (const float*)d_in[4];
    const float* b1  = (const float*)d_in[5];
    const float* W2  = (const float*)d_in[6];
    const float* as2 = (const float*)d_in[7];
    const float* ad2 = (const float*)d_in[8];
    const float* b2  = (const float*)d_in[9];
    const float* W3  = (const float*)d_in[10];
    const float* as3 = (const float*)d_in[11];
    const float* ad3 = (const float*)d_in[12];
    const float* b3  = (const float*)d_in[13];

    const int fhid = in_sizes[3];        // 64
    const int fin  = in_sizes[2] / fhid; // 128
    const int fo3  = in_sizes[11];       // 32
    const int n    = in_sizes[0] / fin;  // 100000
    const int E    = in_sizes[1] / 2;    // 1,600,000
    const int Etot = E + n;
    const int nsb  = (n + 511) >> 9;

    const int* esrc = eidx;
    const int* edst = eidx + E;

    float* out = (float*)d_out;
    float* h1  = out + (size_t)n * fo3;
    float* h2  = h1 + (size_t)n * fhid;

    // ws: sbhist[256] | sbbase[260] | sbcur[256] | row_end[n] | packed1[Etot]
    //     | col[Etot] | hA[n*fhid bf16] | a_sA[n] | a_dA[n]
    //     | (fused extra:) hB[n*fhid bf16] | a_sB[n] | a_dB[n]
    int* sbhist   = (int*)d_ws;
    int* sbbase   = sbhist + 256;
    int* sbcur    = sbbase + 260;
    int* row_end  = sbcur + 256;
    int* packed1  = row_end + n;
    int* col      = packed1 + Etot;
    __hip_bfloat16* hA = (__hip_bfloat16*)(col + Etot);
    float* a_sA   = (float*)(hA + (size_t)n * fhid);
    float* a_dA   = a_sA + n;
    __hip_bfloat16* hB = (__hip_bfloat16*)(a_dA + n);
    float* a_sB   = (float*)(hB + (size_t)n * fhid);
    float* a_dB   = a_sB + n;
    size_t need_fused = (size_t)((char*)(a_dB + n) - (char*)d_ws);

    const int nchunks = (Etot + CB_CHUNK - 1) / CB_CHUNK;

    // ---- CSR build (shared by all layers) ----
    hipMemsetAsync(sbhist, 0, 256 * 4, stream);
    sb_hist<<<1024, 256, 0, stream>>>(edst, E, n, sbhist);
    sb_scan<<<1, 256, 0, stream>>>(sbhist, nsb, Etot, sbbase, sbcur);
    chunk_bin<<<nchunks, 256, 0, stream>>>(esrc, edst, E, n, nsb, sbcur, packed1);
    sb_sort2<<<nsb, 256, 0, stream>>>(sbbase, packed1, col, row_end, n);

    const int NLB = (n + 63) / 64;
    const int AGG64B = (n + 15) / 16;    // 16 nodes / block
    const int AGG32B = (n + 31) / 32;    // 32 nodes / block

    if (ws_size >= need_fused) {
        // Fused path: L1 agg + NL2 fused; L2 agg + NL3 fused; L3 agg plain.
        node_linear<128, 64><<<NLB, 256, 0, stream>>>(x, W1, as1, ad1, hA, a_sA, a_dA, n);
        gat_aggregate<64, 64><<<AGG64B, 256, 0, stream>>>(
            row_end, col, a_sA, a_dA, hA, b1, h1, n, 1,
            W2, as2, ad2, hB, a_sB, a_dB);
        gat_aggregate<64, 32><<<AGG64B, 256, 0, stream>>>(
            row_end, col, a_sB, a_dB, hB, b2, h2, n, 1,
            W3, as3, ad3, hA, a_sA, a_dA);
        gat_aggregate<32, 0><<<AGG32B, 256, 0, stream>>>(
            row_end, col, a_sA, a_dA, hA, b3, out, n, 0,
            nullptr, nullptr, nullptr, nullptr, nullptr, nullptr);
    } else {
        // Fallback (round-18 structure): separate node_linear per layer.
        node_linear<128, 64><<<NLB, 256, 0, stream>>>(x, W1, as1, ad1, hA, a_sA, a_dA, n);
        gat_aggregate<64, 0><<<AGG64B, 256, 0, stream>>>(
            row_end, col, a_sA, a_dA, hA, b1, h1, n, 1,
            nullptr, nullptr, nullptr, nullptr, nullptr, nullptr);
        node_linear<64, 64><<<NLB, 256, 0, stream>>>(h1, W2, as2, ad2, hA, a_sA, a_dA, n);
        gat_aggregate<64, 0><<<AGG64B, 256, 0, stream>>>(
            row_end, col, a_sA, a_dA, hA, b2, h2, n, 1,
            nullptr, nullptr, nullptr, nullptr, nullptr, nullptr);
        node_linear<64, 32><<<NLB, 256, 0, stream>>>(h2, W3, as3, ad3, hA, a_sA, a_dA, n);
        gat_aggregate<32, 0><<<AGG32B, 256, 0, stream>>>(
            row_end, col, a_sA, a_dA, hA, b3, out, n, 0,
            nullptr, nullptr, nullptr, nullptr, nullptr, nullptr);
    }
}